// Round 12
// baseline (680.099 us; speedup 1.0000x reference)
//
#include <hip/hip_runtime.h>

// BiCLSTM: S=16,B=4,Cin=32,Co=32,H=W=128. fp32 in/out.
// FP16 MFMA implicit-GEMM (r8 skeleton), HBM-efficiency round:
//  - c-state fp16 (r9-proven bit-identical result)
//  - h written coalesced (LDS-transposed 16B streams incl. halo strips), no 2B scatter
//  - out nontemporal; B per-ks global_load_lds dbuf; x pre-tiled fp16.
#define S_ 16
#define B_ 4
#define H_ 128
#define W_ 128
#define HW_ (H_ * W_)
#define NPOS 324               // 18*18
#define TILE_ELEMS (NPOS * 32) // fp16 elems per tile A-block
#define HS 40                  // hsh stride (halfwords) per pixel: bank-spread, 16B-aligned

typedef __attribute__((ext_vector_type(8))) _Float16 half8;
typedef __attribute__((ext_vector_type(4))) _Float16 half4;
typedef __attribute__((ext_vector_type(4))) float f32x4;

__device__ __forceinline__ float sigf(float x) { return 1.f / (1.f + __expf(-x)); }
__device__ __forceinline__ float tanhf_(float x) { return 2.f / (1.f + __expf(-2.f * x)) - 1.f; }

__device__ __forceinline__ void gl2lds16(const _Float16* g, _Float16* l) {
    __builtin_amdgcn_global_load_lds(
        (const __attribute__((address_space(1))) unsigned int*)g,
        (__attribute__((address_space(3))) unsigned int*)l, 16, 0, 0);
}

// ---- B-fragment packing: [dir][ks=18][nf=8][lane=64][e=8] fp16 ----
__global__ void prep_pack(const float* __restrict__ Wf, const float* __restrict__ Wb,
                          _Float16* __restrict__ wpk) {
    int id = blockIdx.x * 256 + threadIdx.x;  // 18432
    if (id >= 18432) return;
    int l = id & 63;
    int nf = (id >> 6) & 7;
    int ks = (id >> 9) % 18;
    int d = id / 9216;
    const float* Wsrc = d ? Wb : Wf;
    int tap = ks >> 1, half = ks & 1;
    int dy = tap / 3, dx = tap - dy * 3;
    int co = nf * 16 + (l & 15);
    _Float16* dst = wpk + (size_t)d * 73728 + ((size_t)(ks * 8 + nf) * 64 + l) * 8;
#pragma unroll
    for (int e = 0; e < 8; ++e) {
        int ci = half * 32 + (l >> 4) * 8 + e;
        dst[e] = (_Float16)Wsrc[((co * 64 + ci) * 3 + dy) * 3 + dx];
    }
}

// ---- One-time x -> tile layout [ts][b][tile][pos324][ci32] fp16, coalesced ----
__global__ void prep_xtiles(const float* __restrict__ x, _Float16* __restrict__ xt) {
    int id = blockIdx.x * 256 + threadIdx.x;  // 5,308,416
    if (id >= 16 * 4 * 64 * NPOS * 4) return;
    int cb = id & 3;
    int u = id >> 2;
    int pos = u % NPOS;
    int v = u / NPOS;
    int tile = v & 63;
    v >>= 6;
    int b = v & 3;
    int ts = v >> 2;
    int r = pos / 18, cc = pos - r * 18;
    int gy = (tile >> 3) * 16 + r - 1;
    int gx = (tile & 7) * 16 + cc - 1;
    bool inb = ((unsigned)gy < 128u) && ((unsigned)gx < 128u);
    const float* g = x + ((size_t)(ts * 4 + b) * 32 + cb * 8) * HW_ + (size_t)gy * W_ + gx;
    half8 vv;
#pragma unroll
    for (int e = 0; e < 8; ++e)
        vv[e] = inb ? (_Float16)__builtin_nontemporal_load(g + e * HW_) : (_Float16)0.f;
    *(half8*)(xt + (size_t)u * 32 + cb * 8) = vv;
}

__device__ __forceinline__ half8 lda(const _Float16* __restrict__ base, int m, int dy,
                                     int dx, int px, int kg, int wq) {
    return *(const half8*)(base + (size_t)(((wq * 4 + m + dy) * 18) + px + dx) * 32 + kg * 8);
}
__device__ __forceinline__ half8 ldb(const _Float16* __restrict__ bw, int ks, int nf, int lane) {
    return *(const half8*)(bw + (size_t)(ks * 8 + nf) * 512 + lane * 8);
}

// One timestep, both directions. grid (64, 8): x = tile, y = dir*4+b. 256 thr.
__global__ __launch_bounds__(256, 2)
void convlstm_step(const _Float16* __restrict__ xtiles,
                   const _Float16* __restrict__ hin,
                   _Float16* __restrict__ hout,
                   const _Float16* __restrict__ wpk,
                   const float* __restrict__ biasf, const float* __restrict__ biasb,
                   _Float16* __restrict__ cst,          // fp16 c-state [dirb][32][HW]
                   float* __restrict__ out, int t) {
    const int tile = blockIdx.x;
    const int dirb = blockIdx.y;
    const int dir = dirb >> 2, b = dirb & 3;
    const int ts = dir ? (S_ - 1 - t) : t;

    const _Float16* base_x = xtiles + ((size_t)(ts * 4 + b) * 64 + tile) * TILE_ELEMS;
    const _Float16* base_h = hin + ((size_t)dirb * 64 + tile) * TILE_ELEMS;
    _Float16* hob = hout + (size_t)dirb * 64 * TILE_ELEMS;
    const _Float16* bw = wpk + (size_t)dir * 73728;
    const float* bias = dir ? biasb : biasf;
    _Float16* cbase = cst + (size_t)dirb * 32 * HW_;
    float* outp = out + ((size_t)(t * 4 + b) * 64 + dir * 32) * HW_;

    __shared__ alignas(16) _Float16 bsh[2][8][64][8];   // 16,384 B B-frag dbuf
    __shared__ alignas(16) _Float16 hsh[256 * HS];      // 20,480 B h staging

    const int tid = threadIdx.x;
    const int lane = tid & 63, wq = tid >> 6;
    const int px = lane & 15, kg = lane >> 4;

    f32x4 acc[4][8];
#pragma unroll
    for (int m = 0; m < 4; ++m)
#pragma unroll
        for (int nf = 0; nf < 8; ++nf) acc[m][nf] = (f32x4)(0.f);

    if (t == 0) {
#pragma unroll 1
        for (int tap = 0; tap < 9; ++tap) {
            int dy = tap / 3, dx = tap - dy * 3;
            half8 a[4];
#pragma unroll
            for (int m = 0; m < 4; ++m) a[m] = lda(base_x, m, dy, dx, px, kg, wq);
#pragma unroll
            for (int nf = 0; nf < 8; ++nf) {
                half8 bb8 = ldb(bw, tap * 2, nf, lane);
#pragma unroll
                for (int m = 0; m < 4; ++m)
                    acc[m][nf] = __builtin_amdgcn_mfma_f32_16x16x32_f16(a[m], bb8, acc[m][nf], 0, 0, 0);
            }
        }
    } else {
        half8 aP[4], aQ[4];
        {
            const _Float16* gs = bw + ((size_t)(0 * 8 + wq * 2) * 64 + lane) * 8;
            gl2lds16(gs, &bsh[0][wq * 2][0][0]);
            gl2lds16(gs + 512, &bsh[0][wq * 2 + 1][0][0]);
#pragma unroll
            for (int m = 0; m < 4; ++m) aP[m] = lda(base_x, m, 0, 0, px, kg, wq);
        }
        auto body = [&](int ks, half8(&acur)[4], half8(&anxt)[4]) {
            __syncthreads();
            if (ks < 17) {
                const int ksn = ks + 1;
                const _Float16* gs = bw + ((size_t)(ksn * 8 + wq * 2) * 64 + lane) * 8;
                gl2lds16(gs, &bsh[ksn & 1][wq * 2][0][0]);
                gl2lds16(gs + 512, &bsh[ksn & 1][wq * 2 + 1][0][0]);
                const int tapn = ksn >> 1;
                const int dyn_ = tapn / 3, dxn = tapn - dyn_ * 3;
                const _Float16* an = (ksn & 1) ? base_h : base_x;
#pragma unroll
                for (int m = 0; m < 4; ++m) anxt[m] = lda(an, m, dyn_, dxn, px, kg, wq);
            }
            const _Float16* lb = &bsh[ks & 1][0][0][0];
#pragma unroll
            for (int nf = 0; nf < 8; ++nf) {
                half8 bb8 = *(const half8*)(lb + nf * 512 + lane * 8);
#pragma unroll
                for (int m = 0; m < 4; ++m)
                    acc[m][nf] = __builtin_amdgcn_mfma_f32_16x16x32_f16(acur[m], bb8, acc[m][nf], 0, 0, 0);
            }
        };
#pragma unroll 1
        for (int ks = 0; ks < 18; ks += 2) {
            body(ks, aP, aQ);
            body(ks + 1, aQ, aP);
        }
    }

    // Epilogue: gates -> c (fp16, 8B), out (nt 16B), h -> LDS staging.
    const int q0 = px;
    const int gx0 = (tile & 7) * 16, gy0 = (tile >> 3) * 16;
    const int tx = tile & 7, ty_ = tile >> 3;
    const int lx0 = kg * 4;

    float bI[2], bF[2], bO[2], bG[2];
#pragma unroll
    for (int qs = 0; qs < 2; ++qs) {
        bI[qs] = bias[qs * 16 + q0];
        bF[qs] = bias[32 + qs * 16 + q0];
        bO[qs] = bias[64 + qs * 16 + q0];
        bG[qs] = bias[96 + qs * 16 + q0];
    }
#pragma unroll
    for (int m = 0; m < 4; ++m) {
        const int ly = wq * 4 + m;
        const int gy = gy0 + ly;
#pragma unroll
        for (int qs = 0; qs < 2; ++qs) {
            const int q = qs * 16 + q0;
            f32x4 zi = acc[m][qs], zf = acc[m][2 + qs], zo = acc[m][4 + qs], zg = acc[m][6 + qs];
            size_t off = (size_t)q * HW_ + (size_t)gy * W_ + gx0 + lx0;
            half4 cold4 = (half4)((_Float16)0.f);
            if (t) cold4 = *(const half4*)(cbase + off);
            half4 cn4;
            f32x4 hn;
#pragma unroll
            for (int r = 0; r < 4; ++r) {
                float I = sigf(zi[r] + bI[qs]);
                float F = sigf(zf[r] + bF[qs]);
                float O = sigf(zo[r] + bO[qs]);
                float G = tanhf_(zg[r] + bG[qs]);
                float cnr = F * (float)cold4[r] + I * G;
                cn4[r] = (_Float16)cnr;
                hn[r] = O * tanhf_(cnr);
            }
            *(half4*)(cbase + off) = cn4;
            __builtin_nontemporal_store(hn, (f32x4*)(outp + off));
#pragma unroll
            for (int r = 0; r < 4; ++r)
                hsh[(ly * 16 + lx0 + r) * HS + q] = (_Float16)hn[r];
        }
    }
    __syncthreads();

    // Coalesced h write-out: own interior + neighbor halo strips (block-uniform branches).
    _Float16* ownb = hob + (size_t)tile * TILE_ELEMS;
#pragma unroll 1
    for (int c = tid; c < 1024; c += 256) {           // own 16x16 core, 16B chunks
        int pxi = c >> 2, c8 = c & 3;
        int ly = pxi >> 4, lx = pxi & 15;
        *(half8*)(ownb + (size_t)((ly + 1) * 18 + lx + 1) * 32 + c8 * 8) =
            *(const half8*)(hsh + pxi * HS + c8 * 8);
    }
    {
        const int sid = tid >> 6;                     // strip id 0..3
        const int st = tid & 63;
        const int rr = st >> 2, c8 = st & 3;
        if (sid == 0 && tx > 0)                       // left edge -> tile-1 col 17
            *(half8*)(hob + (size_t)(tile - 1) * TILE_ELEMS + (size_t)((rr + 1) * 18 + 17) * 32 + c8 * 8) =
                *(const half8*)(hsh + (rr * 16 + 0) * HS + c8 * 8);
        if (sid == 1 && tx < 7)                       // right edge -> tile+1 col 0
            *(half8*)(hob + (size_t)(tile + 1) * TILE_ELEMS + (size_t)((rr + 1) * 18 + 0) * 32 + c8 * 8) =
                *(const half8*)(hsh + (rr * 16 + 15) * HS + c8 * 8);
        if (sid == 2 && ty_ > 0)                      // top edge -> tile-8 row 17
            *(half8*)(hob + (size_t)(tile - 8) * TILE_ELEMS + (size_t)(17 * 18 + rr + 1) * 32 + c8 * 8) =
                *(const half8*)(hsh + (0 * 16 + rr) * HS + c8 * 8);
        if (sid == 3 && ty_ < 7)                      // bottom edge -> tile+8 row 0
            *(half8*)(hob + (size_t)(tile + 8) * TILE_ELEMS + (size_t)(0 * 18 + rr + 1) * 32 + c8 * 8) =
                *(const half8*)(hsh + (15 * 16 + rr) * HS + c8 * 8);
    }
    if (tid < 16) {                                   // 4 corners
        const int cid = tid >> 2, c8 = tid & 3;
        if (cid == 0 && tx > 0 && ty_ > 0)
            *(half8*)(hob + (size_t)(tile - 9) * TILE_ELEMS + (size_t)(17 * 18 + 17) * 32 + c8 * 8) =
                *(const half8*)(hsh + 0 * HS + c8 * 8);
        if (cid == 1 && tx < 7 && ty_ > 0)
            *(half8*)(hob + (size_t)(tile - 7) * TILE_ELEMS + (size_t)(17 * 18 + 0) * 32 + c8 * 8) =
                *(const half8*)(hsh + 15 * HS + c8 * 8);
        if (cid == 2 && tx > 0 && ty_ < 7)
            *(half8*)(hob + (size_t)(tile + 7) * TILE_ELEMS + (size_t)(0 * 18 + 17) * 32 + c8 * 8) =
                *(const half8*)(hsh + 240 * HS + c8 * 8);
        if (cid == 3 && tx < 7 && ty_ < 7)
            *(half8*)(hob + (size_t)(tile + 9) * TILE_ELEMS + (size_t)(0 * 18 + 0) * 32 + c8 * 8) =
                *(const half8*)(hsh + 255 * HS + c8 * 8);
    }
}

extern "C" void kernel_launch(void* const* d_in, const int* in_sizes, int n_in,
                              void* d_out, int out_size, void* d_ws, size_t ws_size,
                              hipStream_t stream) {
    const float* x  = (const float*)d_in[0];
    const float* Wf = (const float*)d_in[1];
    const float* bf = (const float*)d_in[2];
    const float* Wb = (const float*)d_in[3];
    const float* bb = (const float*)d_in[4];
    float* out = (float*)d_out;
    char* ws = (char*)d_ws;

    const size_t OFF_WPK = 0;                       // 294,912
    const size_t OFF_XT  = 327680;                  // 84,934,656
    const size_t OFF_H0  = OFF_XT + 84934656;       // 10,616,832
    const size_t OFF_H1  = OFF_H0 + 10616832;       // 10,616,832
    const size_t OFF_C   = OFF_H1 + 10616832;       // 8,388,608 (fp16)

    _Float16* wpk = (_Float16*)(ws + OFF_WPK);
    _Float16* xt  = (_Float16*)(ws + OFF_XT);
    _Float16* hb[2] = { (_Float16*)(ws + OFF_H0), (_Float16*)(ws + OFF_H1) };
    _Float16* cst = (_Float16*)(ws + OFF_C);

    // Zero h ping-pong buffers once (out-of-image halo slots must read as 0).
    hipMemsetAsync(ws + OFF_H0, 0, 2u * 10616832u, stream);

    prep_pack<<<dim3(72), dim3(256), 0, stream>>>(Wf, Wb, wpk);
    prep_xtiles<<<dim3(20736), dim3(256), 0, stream>>>(x, xt);

    for (int t = 0; t < S_; ++t) {
        convlstm_step<<<dim3(64, 8), dim3(256), 0, stream>>>(
            xt, hb[(t + 1) & 1], hb[t & 1], wpk, bf, bb, cst, out, t);
    }
}

// Round 13
// 608.132 us; speedup vs baseline: 1.1183x; 1.1183x over previous
//
#include <hip/hip_runtime.h>

// BiCLSTM: S=16,B=4,Cin=32,Co=32,H=W=128. fp32 in/out.
// FP16 MFMA implicit-GEMM, deep-pipeline round:
//  - B weights fully LDS-resident (144 KiB dynamic), staged once, K-loop has NO barriers
//  - 512-thr blocks, 16x32 tiles, 256 blocks = 1/CU; acc[4][8]
//  - A-operand rolling prefetch depth 4 (16 outstanding 16B loads/lane)
//  - x pre-tiled [t][b][tile][pos 18x34][ci32] fp16; h scatter; c fp16; nt out.
#define S_ 16
#define B_ 4
#define H_ 128
#define W_ 128
#define HW_ (H_ * W_)
#define AH 18
#define AW 34
#define NPOS (AH * AW)          // 612
#define TILE_ELEMS (NPOS * 32)  // 19584 halves per tile A-block

typedef __attribute__((ext_vector_type(8))) _Float16 half8;
typedef __attribute__((ext_vector_type(4))) _Float16 half4;
typedef __attribute__((ext_vector_type(4))) float f32x4;

__device__ __forceinline__ float sigf(float x) { return 1.f / (1.f + __expf(-x)); }
__device__ __forceinline__ float tanhf_(float x) { return 2.f / (1.f + __expf(-2.f * x)) - 1.f; }

__device__ __forceinline__ void gl2lds16(const _Float16* g, _Float16* l) {
    __builtin_amdgcn_global_load_lds(
        (const __attribute__((address_space(1))) unsigned int*)g,
        (__attribute__((address_space(3))) unsigned int*)l, 16, 0, 0);
}

// ---- B-fragment packing: [dir][ks=18][nf=8][lane=64][e=8] fp16 (unchanged) ----
__global__ void prep_pack(const float* __restrict__ Wf, const float* __restrict__ Wb,
                          _Float16* __restrict__ wpk) {
    int id = blockIdx.x * 256 + threadIdx.x;  // 18432
    if (id >= 18432) return;
    int l = id & 63;
    int nf = (id >> 6) & 7;
    int ks = (id >> 9) % 18;
    int d = id / 9216;
    const float* Wsrc = d ? Wb : Wf;
    int tap = ks >> 1, half = ks & 1;
    int dy = tap / 3, dx = tap - dy * 3;
    int co = nf * 16 + (l & 15);
    _Float16* dst = wpk + (size_t)d * 73728 + ((size_t)(ks * 8 + nf) * 64 + l) * 8;
#pragma unroll
    for (int e = 0; e < 8; ++e) {
        int ci = half * 32 + (l >> 4) * 8 + e;
        dst[e] = (_Float16)Wsrc[((co * 64 + ci) * 3 + dy) * 3 + dx];
    }
}

// ---- One-time x -> 16x32-tile layout [ts][b][tile32][pos612][ci32] fp16 ----
__global__ void prep_xtiles(const float* __restrict__ x, _Float16* __restrict__ xt) {
    int id = blockIdx.x * 256 + threadIdx.x;  // 16*4*32*612*4 = 5,013,504
    if (id >= 16 * 4 * 32 * NPOS * 4) return;
    int cb = id & 3;
    int u = id >> 2;            // [ts][b][tile][pos]
    int pos = u % NPOS;
    int v = u / NPOS;
    int tile = v & 31;
    v >>= 5;
    int b = v & 3;
    int ts = v >> 2;
    int ar = pos / AW, ac = pos - ar * AW;
    int gy = (tile >> 2) * 16 + ar - 1;      // ty = tile>>2 (8 tiles of 16 rows)
    int gx = (tile & 3) * 32 + ac - 1;       // tx = tile&3  (4 tiles of 32 cols)
    bool inb = ((unsigned)gy < 128u) && ((unsigned)gx < 128u);
    const float* g = x + ((size_t)(ts * 4 + b) * 32 + cb * 8) * HW_ + (size_t)gy * W_ + gx;
    half8 vv;
#pragma unroll
    for (int e = 0; e < 8; ++e)
        vv[e] = inb ? (_Float16)__builtin_nontemporal_load(g + e * HW_) : (_Float16)0.f;
    *(half8*)(xt + (size_t)u * 32 + cb * 8) = vv;
}

// A-frag loader. m-frag f: row = wq*2+(f>>1), colgroup = f&1.
__device__ __forceinline__ half8 lda(const _Float16* __restrict__ base, int f, int dy,
                                     int dx, int px, int kg, int wq) {
    int pos = (wq * 2 + (f >> 1) + dy) * AW + (f & 1) * 16 + px + dx;
    return *(const half8*)(base + (size_t)pos * 32 + kg * 8);
}

extern __shared__ _Float16 bsh[];  // 147,456 B: [ks*8+nf][lane][e=8], one dir

// One timestep, both directions. grid (32, 8): x = tile, y = dir*4+b. 512 thr.
__global__ __launch_bounds__(512, 1)
void convlstm_step(const _Float16* __restrict__ xtiles,
                   const _Float16* __restrict__ hin,
                   _Float16* __restrict__ hout,
                   const _Float16* __restrict__ wpk,
                   const float* __restrict__ biasf, const float* __restrict__ biasb,
                   _Float16* __restrict__ cst,          // fp16 c-state [dirb][32][HW]
                   float* __restrict__ out, int t) {
    const int tile = blockIdx.x;
    const int dirb = blockIdx.y;
    const int dir = dirb >> 2, b = dirb & 3;
    const int ts = dir ? (S_ - 1 - t) : t;

    const _Float16* base_x = xtiles + ((size_t)(ts * 4 + b) * 32 + tile) * TILE_ELEMS;
    const _Float16* base_h = hin + ((size_t)dirb * 32 + tile) * TILE_ELEMS;
    _Float16* hob = hout + (size_t)dirb * 32 * TILE_ELEMS;
    const _Float16* bw = wpk + (size_t)dir * 73728;
    const float* bias = dir ? biasb : biasf;
    _Float16* cbase = cst + (size_t)dirb * 32 * HW_;
    float* outp = out + ((size_t)(t * 4 + b) * 64 + dir * 32) * HW_;

    const int tid = threadIdx.x;
    const int lane = tid & 63, wq = tid >> 6;   // wq 0..7
    const int px = lane & 15, kg = lane >> 4;

    // Stage FULL B for this dir into LDS: 9216 chunks of 16B, 18 per thread.
#pragma unroll
    for (int k = 0; k < 18; ++k) {
        int wb = k * 512 + (tid & ~63);          // wave-uniform chunk base
        gl2lds16(bw + ((size_t)wb + lane) * 8, bsh + (size_t)wb * 8);
    }

    f32x4 acc[4][8];
#pragma unroll
    for (int f = 0; f < 4; ++f)
#pragma unroll
        for (int nf = 0; nf < 8; ++nf) acc[f][nf] = (f32x4)(0.f);

    half8 abuf[4][4];  // [slot][f], rolling depth 4

    if (t == 0) {
        // x-half only: 9 taps.
#pragma unroll
        for (int tp = 0; tp < 4; ++tp) {
            int dy = tp / 3, dx = tp - dy * 3;
#pragma unroll
            for (int f = 0; f < 4; ++f) abuf[tp][f] = lda(base_x, f, dy, dx, px, kg, wq);
        }
        __syncthreads();
#pragma unroll
        for (int tap = 0; tap < 9; ++tap) {
            const int slot = tap & 3;
#pragma unroll
            for (int nf = 0; nf < 8; ++nf) {
                half8 b8 = *(const half8*)(bsh + ((size_t)((tap * 2) * 8 + nf) << 9) + (lane << 3));
#pragma unroll
                for (int f = 0; f < 4; ++f)
                    acc[f][nf] = __builtin_amdgcn_mfma_f32_16x16x32_f16(abuf[slot][f], b8, acc[f][nf], 0, 0, 0);
            }
            if (tap + 4 < 9) {
                const int tn = tap + 4;
                const int dyn_ = tn / 3, dxn = tn - dyn_ * 3;
#pragma unroll
                for (int f = 0; f < 4; ++f) abuf[slot][f] = lda(base_x, f, dyn_, dxn, px, kg, wq);
            }
        }
    } else {
        // 18 ks: even = x, odd = h. Rolling prefetch depth 4; no in-loop barriers.
#pragma unroll
        for (int k0 = 0; k0 < 4; ++k0) {
            int tp = k0 >> 1;
            int dy = tp / 3, dx = tp - dy * 3;
            const _Float16* src = (k0 & 1) ? base_h : base_x;
#pragma unroll
            for (int f = 0; f < 4; ++f) abuf[k0][f] = lda(src, f, dy, dx, px, kg, wq);
        }
        __syncthreads();
#pragma unroll
        for (int ks = 0; ks < 18; ++ks) {
            const int slot = ks & 3;
#pragma unroll
            for (int nf = 0; nf < 8; ++nf) {
                half8 b8 = *(const half8*)(bsh + ((size_t)(ks * 8 + nf) << 9) + (lane << 3));
#pragma unroll
                for (int f = 0; f < 4; ++f)
                    acc[f][nf] = __builtin_amdgcn_mfma_f32_16x16x32_f16(abuf[slot][f], b8, acc[f][nf], 0, 0, 0);
            }
            if (ks + 4 < 18) {
                const int kn = ks + 4;
                const int tn = kn >> 1;
                const int dyn_ = tn / 3, dxn = tn - dyn_ * 3;
                const _Float16* src = (kn & 1) ? base_h : base_x;
#pragma unroll
                for (int f = 0; f < 4; ++f) abuf[slot][f] = lda(src, f, dyn_, dxn, px, kg, wq);
            }
        }
    }

    // Epilogue. m-frag f -> row = wq*2+(f>>1), cols (f&1)*16 + kg*4 + r. q0 = px.
    const int q0 = px;
    const int gx0 = (tile & 3) * 32, gy0 = (tile >> 2) * 16;
    const int tx = tile & 3, ty_ = tile >> 2;
    const int lx0 = kg * 4;

    float bI[2], bF[2], bO[2], bG[2];
#pragma unroll
    for (int qs = 0; qs < 2; ++qs) {
        bI[qs] = bias[qs * 16 + q0];
        bF[qs] = bias[32 + qs * 16 + q0];
        bO[qs] = bias[64 + qs * 16 + q0];
        bG[qs] = bias[96 + qs * 16 + q0];
    }
#pragma unroll
    for (int f = 0; f < 4; ++f) {
        const int row = wq * 2 + (f >> 1);       // 0..15 in tile
        const int gy = gy0 + row;
        const int colb = (f & 1) * 16 + lx0;     // 0..28 in tile (step 4)
#pragma unroll
        for (int qs = 0; qs < 2; ++qs) {
            const int q = qs * 16 + q0;
            f32x4 zi = acc[f][qs], zf = acc[f][2 + qs], zo = acc[f][4 + qs], zg = acc[f][6 + qs];
            size_t off = (size_t)q * HW_ + (size_t)gy * W_ + gx0 + colb;
            half4 cold4 = (half4)((_Float16)0.f);
            if (t) cold4 = *(const half4*)(cbase + off);
            half4 cn4;
            f32x4 hn;
#pragma unroll
            for (int r = 0; r < 4; ++r) {
                float I = sigf(zi[r] + bI[qs]);
                float F = sigf(zf[r] + bF[qs]);
                float O = sigf(zo[r] + bO[qs]);
                float G = tanhf_(zg[r] + bG[qs]);
                float cnr = F * (float)cold4[r] + I * G;
                cn4[r] = (_Float16)cnr;
                hn[r] = O * tanhf_(cnr);
            }
            *(half4*)(cbase + off) = cn4;
            __builtin_nontemporal_store(hn, (f32x4*)(outp + off));
            // Scatter h(t) fp16 into tile-format write buffer (own + halo neighbors).
#pragma unroll
            for (int r = 0; r < 4; ++r) {
                _Float16 hh = (_Float16)hn[r];
                int col = colb + r;              // 0..31
                hob[(size_t)tile * TILE_ELEMS + (size_t)((row + 1) * AW + col + 1) * 32 + q] = hh;
                bool Le = (col == 0) && (tx > 0);
                bool Re = (col == 31) && (tx < 3);
                bool Te = (row == 0) && (ty_ > 0);
                bool Be = (row == 15) && (ty_ < 7);
                if (Le) hob[(size_t)(tile - 1) * TILE_ELEMS + (size_t)((row + 1) * AW + 33) * 32 + q] = hh;
                if (Re) hob[(size_t)(tile + 1) * TILE_ELEMS + (size_t)((row + 1) * AW + 0) * 32 + q] = hh;
                if (Te) hob[(size_t)(tile - 4) * TILE_ELEMS + (size_t)(17 * AW + col + 1) * 32 + q] = hh;
                if (Be) hob[(size_t)(tile + 4) * TILE_ELEMS + (size_t)(0 * AW + col + 1) * 32 + q] = hh;
                if (Te && Le) hob[(size_t)(tile - 5) * TILE_ELEMS + (size_t)(17 * AW + 33) * 32 + q] = hh;
                if (Te && Re) hob[(size_t)(tile - 3) * TILE_ELEMS + (size_t)(17 * AW + 0) * 32 + q] = hh;
                if (Be && Le) hob[(size_t)(tile + 3) * TILE_ELEMS + (size_t)(0 * AW + 33) * 32 + q] = hh;
                if (Be && Re) hob[(size_t)(tile + 5) * TILE_ELEMS + (size_t)(0 * AW + 0) * 32 + q] = hh;
            }
        }
    }
}

extern "C" void kernel_launch(void* const* d_in, const int* in_sizes, int n_in,
                              void* d_out, int out_size, void* d_ws, size_t ws_size,
                              hipStream_t stream) {
    const float* x  = (const float*)d_in[0];
    const float* Wf = (const float*)d_in[1];
    const float* bf = (const float*)d_in[2];
    const float* Wb = (const float*)d_in[3];
    const float* bb = (const float*)d_in[4];
    float* out = (float*)d_out;
    char* ws = (char*)d_ws;

    const size_t OFF_WPK = 0;                         // 294,912
    const size_t OFF_XT  = 327680;                    // 80,216,064
    const size_t OFF_H0  = OFF_XT + 80216064;         // 10,027,008
    const size_t OFF_H1  = OFF_H0 + 10027008;         // 10,027,008
    const size_t OFF_C   = OFF_H1 + 10027008;         // 8,388,608 (fp16)

    _Float16* wpk = (_Float16*)(ws + OFF_WPK);
    _Float16* xt  = (_Float16*)(ws + OFF_XT);
    _Float16* hb[2] = { (_Float16*)(ws + OFF_H0), (_Float16*)(ws + OFF_H1) };
    _Float16* cst = (_Float16*)(ws + OFF_C);

    hipFuncSetAttribute((const void*)convlstm_step,
                        hipFuncAttributeMaxDynamicSharedMemorySize, 147456);

    // Zero h ping-pong buffers once (out-of-image halo slots must read as 0).
    hipMemsetAsync(ws + OFF_H0, 0, 2u * 10027008u, stream);

    prep_pack<<<dim3(72), dim3(256), 0, stream>>>(Wf, Wb, wpk);
    prep_xtiles<<<dim3(19584), dim3(256), 0, stream>>>(x, xt);

    for (int t = 0; t < S_; ++t) {
        convlstm_step<<<dim3(32, 8), dim3(512), 147456, stream>>>(
            xt, hb[(t + 1) & 1], hb[t & 1], wpk, bf, bb, cst, out, t);
    }
}

// Round 14
// 604.410 us; speedup vs baseline: 1.1252x; 1.0062x over previous
//
#include <hip/hip_runtime.h>

// BiCLSTM: S=16,B=4,Cin=32,Co=32,H=W=128. fp32 in/out.
// FP16 MFMA implicit-GEMM, XCD-locality round:
//  - grid (8,32): blockIdx.x = dirb -> bid%8 = dirb -> each (dir,b) pinned to ONE XCD;
//    its h ping-pong + c stay resident in that XCD's 4MB L2 for all 16 steps
//  - x A-loads + out stores nontemporal (stream; don't evict h/c from L2)
//  - B fully LDS-resident (144 KiB), barrier-free K-loop, depth-4 A prefetch (r13)
#define S_ 16
#define B_ 4
#define H_ 128
#define W_ 128
#define HW_ (H_ * W_)
#define AH 18
#define AW 34
#define NPOS (AH * AW)          // 612
#define TILE_ELEMS (NPOS * 32)  // 19584 halves per tile A-block

typedef __attribute__((ext_vector_type(8))) _Float16 half8;
typedef __attribute__((ext_vector_type(4))) _Float16 half4;
typedef __attribute__((ext_vector_type(4))) float f32x4;

__device__ __forceinline__ float sigf(float x) { return 1.f / (1.f + __expf(-x)); }
__device__ __forceinline__ float tanhf_(float x) { return 2.f / (1.f + __expf(-2.f * x)) - 1.f; }

__device__ __forceinline__ void gl2lds16(const _Float16* g, _Float16* l) {
    __builtin_amdgcn_global_load_lds(
        (const __attribute__((address_space(1))) unsigned int*)g,
        (__attribute__((address_space(3))) unsigned int*)l, 16, 0, 0);
}

// ---- B-fragment packing: [dir][ks=18][nf=8][lane=64][e=8] fp16 ----
__global__ void prep_pack(const float* __restrict__ Wf, const float* __restrict__ Wb,
                          _Float16* __restrict__ wpk) {
    int id = blockIdx.x * 256 + threadIdx.x;  // 18432
    if (id >= 18432) return;
    int l = id & 63;
    int nf = (id >> 6) & 7;
    int ks = (id >> 9) % 18;
    int d = id / 9216;
    const float* Wsrc = d ? Wb : Wf;
    int tap = ks >> 1, half = ks & 1;
    int dy = tap / 3, dx = tap - dy * 3;
    int co = nf * 16 + (l & 15);
    _Float16* dst = wpk + (size_t)d * 73728 + ((size_t)(ks * 8 + nf) * 64 + l) * 8;
#pragma unroll
    for (int e = 0; e < 8; ++e) {
        int ci = half * 32 + (l >> 4) * 8 + e;
        dst[e] = (_Float16)Wsrc[((co * 64 + ci) * 3 + dy) * 3 + dx];
    }
}

// ---- One-time x -> 16x32-tile layout [ts][b][tile32][pos612][ci32] fp16 ----
__global__ void prep_xtiles(const float* __restrict__ x, _Float16* __restrict__ xt) {
    int id = blockIdx.x * 256 + threadIdx.x;  // 16*4*32*612*4 = 5,013,504
    if (id >= 16 * 4 * 32 * NPOS * 4) return;
    int cb = id & 3;
    int u = id >> 2;            // [ts][b][tile][pos]
    int pos = u % NPOS;
    int v = u / NPOS;
    int tile = v & 31;
    v >>= 5;
    int b = v & 3;
    int ts = v >> 2;
    int ar = pos / AW, ac = pos - ar * AW;
    int gy = (tile >> 2) * 16 + ar - 1;
    int gx = (tile & 3) * 32 + ac - 1;
    bool inb = ((unsigned)gy < 128u) && ((unsigned)gx < 128u);
    const float* g = x + ((size_t)(ts * 4 + b) * 32 + cb * 8) * HW_ + (size_t)gy * W_ + gx;
    half8 vv;
#pragma unroll
    for (int e = 0; e < 8; ++e)
        vv[e] = inb ? (_Float16)__builtin_nontemporal_load(g + e * HW_) : (_Float16)0.f;
    *(half8*)(xt + (size_t)u * 32 + cb * 8) = vv;
}

// A-frag loaders. m-frag f: row = wq*2+(f>>1), colgroup = f&1.
__device__ __forceinline__ half8 lda(const _Float16* __restrict__ base, int f, int dy,
                                     int dx, int px, int kg, int wq) {
    int pos = (wq * 2 + (f >> 1) + dy) * AW + (f & 1) * 16 + px + dx;
    return *(const half8*)(base + (size_t)pos * 32 + kg * 8);
}
__device__ __forceinline__ half8 lda_nt(const _Float16* __restrict__ base, int f, int dy,
                                        int dx, int px, int kg, int wq) {
    int pos = (wq * 2 + (f >> 1) + dy) * AW + (f & 1) * 16 + px + dx;
    return __builtin_nontemporal_load((const half8*)(base + (size_t)pos * 32 + kg * 8));
}

extern __shared__ _Float16 bsh[];  // 147,456 B: [ks*8+nf][lane][e=8], one dir

// One timestep, both directions. grid (8, 32): x = dirb (-> XCD pin), y = tile. 512 thr.
__global__ __launch_bounds__(512, 1)
void convlstm_step(const _Float16* __restrict__ xtiles,
                   const _Float16* __restrict__ hin,
                   _Float16* __restrict__ hout,
                   const _Float16* __restrict__ wpk,
                   const float* __restrict__ biasf, const float* __restrict__ biasb,
                   _Float16* __restrict__ cst,          // fp16 c-state [dirb][32][HW]
                   float* __restrict__ out, int t) {
    const int dirb = blockIdx.x;                        // bid % 8 == dirb -> one XCD
    const int tile = blockIdx.y;
    const int dir = dirb >> 2, b = dirb & 3;
    const int ts = dir ? (S_ - 1 - t) : t;

    const _Float16* base_x = xtiles + ((size_t)(ts * 4 + b) * 32 + tile) * TILE_ELEMS;
    const _Float16* base_h = hin + ((size_t)dirb * 32 + tile) * TILE_ELEMS;
    _Float16* hob = hout + (size_t)dirb * 32 * TILE_ELEMS;
    const _Float16* bw = wpk + (size_t)dir * 73728;
    const float* bias = dir ? biasb : biasf;
    _Float16* cbase = cst + (size_t)dirb * 32 * HW_;
    float* outp = out + ((size_t)(t * 4 + b) * 64 + dir * 32) * HW_;

    const int tid = threadIdx.x;
    const int lane = tid & 63, wq = tid >> 6;   // wq 0..7
    const int px = lane & 15, kg = lane >> 4;

    // Stage FULL B for this dir into LDS: 9216 chunks of 16B, 18 per thread.
#pragma unroll
    for (int k = 0; k < 18; ++k) {
        int wb = k * 512 + (tid & ~63);
        gl2lds16(bw + ((size_t)wb + lane) * 8, bsh + (size_t)wb * 8);
    }

    f32x4 acc[4][8];
#pragma unroll
    for (int f = 0; f < 4; ++f)
#pragma unroll
        for (int nf = 0; nf < 8; ++nf) acc[f][nf] = (f32x4)(0.f);

    half8 abuf[4][4];  // [slot][f], rolling depth 4

    if (t == 0) {
#pragma unroll
        for (int tp = 0; tp < 4; ++tp) {
            int dy = tp / 3, dx = tp - dy * 3;
#pragma unroll
            for (int f = 0; f < 4; ++f) abuf[tp][f] = lda_nt(base_x, f, dy, dx, px, kg, wq);
        }
        __syncthreads();
#pragma unroll
        for (int tap = 0; tap < 9; ++tap) {
            const int slot = tap & 3;
#pragma unroll
            for (int nf = 0; nf < 8; ++nf) {
                half8 b8 = *(const half8*)(bsh + ((size_t)((tap * 2) * 8 + nf) << 9) + (lane << 3));
#pragma unroll
                for (int f = 0; f < 4; ++f)
                    acc[f][nf] = __builtin_amdgcn_mfma_f32_16x16x32_f16(abuf[slot][f], b8, acc[f][nf], 0, 0, 0);
            }
            if (tap + 4 < 9) {
                const int tn = tap + 4;
                const int dyn_ = tn / 3, dxn = tn - dyn_ * 3;
#pragma unroll
                for (int f = 0; f < 4; ++f) abuf[slot][f] = lda_nt(base_x, f, dyn_, dxn, px, kg, wq);
            }
        }
    } else {
        // 18 ks: even = x (nt), odd = h (L2-local). Depth-4 prefetch, no barriers.
#pragma unroll
        for (int k0 = 0; k0 < 4; ++k0) {
            int tp = k0 >> 1;
            int dy = tp / 3, dx = tp - dy * 3;
#pragma unroll
            for (int f = 0; f < 4; ++f)
                abuf[k0][f] = (k0 & 1) ? lda(base_h, f, dy, dx, px, kg, wq)
                                       : lda_nt(base_x, f, dy, dx, px, kg, wq);
        }
        __syncthreads();
#pragma unroll
        for (int ks = 0; ks < 18; ++ks) {
            const int slot = ks & 3;
#pragma unroll
            for (int nf = 0; nf < 8; ++nf) {
                half8 b8 = *(const half8*)(bsh + ((size_t)(ks * 8 + nf) << 9) + (lane << 3));
#pragma unroll
                for (int f = 0; f < 4; ++f)
                    acc[f][nf] = __builtin_amdgcn_mfma_f32_16x16x32_f16(abuf[slot][f], b8, acc[f][nf], 0, 0, 0);
            }
            if (ks + 4 < 18) {
                const int kn = ks + 4;
                const int tn = kn >> 1;
                const int dyn_ = tn / 3, dxn = tn - dyn_ * 3;
#pragma unroll
                for (int f = 0; f < 4; ++f)
                    abuf[slot][f] = (kn & 1) ? lda(base_h, f, dyn_, dxn, px, kg, wq)
                                             : lda_nt(base_x, f, dyn_, dxn, px, kg, wq);
            }
        }
    }

    // Epilogue. m-frag f -> row = wq*2+(f>>1), cols (f&1)*16 + kg*4 + r. q0 = px.
    const int q0 = px;
    const int gx0 = (tile & 3) * 32, gy0 = (tile >> 2) * 16;
    const int tx = tile & 3, ty_ = tile >> 2;
    const int lx0 = kg * 4;

    float bI[2], bF[2], bO[2], bG[2];
#pragma unroll
    for (int qs = 0; qs < 2; ++qs) {
        bI[qs] = bias[qs * 16 + q0];
        bF[qs] = bias[32 + qs * 16 + q0];
        bO[qs] = bias[64 + qs * 16 + q0];
        bG[qs] = bias[96 + qs * 16 + q0];
    }
#pragma unroll
    for (int f = 0; f < 4; ++f) {
        const int row = wq * 2 + (f >> 1);
        const int gy = gy0 + row;
        const int colb = (f & 1) * 16 + lx0;
#pragma unroll
        for (int qs = 0; qs < 2; ++qs) {
            const int q = qs * 16 + q0;
            f32x4 zi = acc[f][qs], zf = acc[f][2 + qs], zo = acc[f][4 + qs], zg = acc[f][6 + qs];
            size_t off = (size_t)q * HW_ + (size_t)gy * W_ + gx0 + colb;
            half4 cold4 = (half4)((_Float16)0.f);
            if (t) cold4 = *(const half4*)(cbase + off);
            half4 cn4;
            f32x4 hn;
#pragma unroll
            for (int r = 0; r < 4; ++r) {
                float I = sigf(zi[r] + bI[qs]);
                float F = sigf(zf[r] + bF[qs]);
                float O = sigf(zo[r] + bO[qs]);
                float G = tanhf_(zg[r] + bG[qs]);
                float cnr = F * (float)cold4[r] + I * G;
                cn4[r] = (_Float16)cnr;
                hn[r] = O * tanhf_(cnr);
            }
            *(half4*)(cbase + off) = cn4;
            __builtin_nontemporal_store(hn, (f32x4*)(outp + off));
#pragma unroll
            for (int r = 0; r < 4; ++r) {
                _Float16 hh = (_Float16)hn[r];
                int col = colb + r;
                hob[(size_t)tile * TILE_ELEMS + (size_t)((row + 1) * AW + col + 1) * 32 + q] = hh;
                bool Le = (col == 0) && (tx > 0);
                bool Re = (col == 31) && (tx < 3);
                bool Te = (row == 0) && (ty_ > 0);
                bool Be = (row == 15) && (ty_ < 7);
                if (Le) hob[(size_t)(tile - 1) * TILE_ELEMS + (size_t)((row + 1) * AW + 33) * 32 + q] = hh;
                if (Re) hob[(size_t)(tile + 1) * TILE_ELEMS + (size_t)((row + 1) * AW + 0) * 32 + q] = hh;
                if (Te) hob[(size_t)(tile - 4) * TILE_ELEMS + (size_t)(17 * AW + col + 1) * 32 + q] = hh;
                if (Be) hob[(size_t)(tile + 4) * TILE_ELEMS + (size_t)(0 * AW + col + 1) * 32 + q] = hh;
                if (Te && Le) hob[(size_t)(tile - 5) * TILE_ELEMS + (size_t)(17 * AW + 33) * 32 + q] = hh;
                if (Te && Re) hob[(size_t)(tile - 3) * TILE_ELEMS + (size_t)(17 * AW + 0) * 32 + q] = hh;
                if (Be && Le) hob[(size_t)(tile + 3) * TILE_ELEMS + (size_t)(0 * AW + 33) * 32 + q] = hh;
                if (Be && Re) hob[(size_t)(tile + 5) * TILE_ELEMS + (size_t)(0 * AW + 0) * 32 + q] = hh;
            }
        }
    }
}

extern "C" void kernel_launch(void* const* d_in, const int* in_sizes, int n_in,
                              void* d_out, int out_size, void* d_ws, size_t ws_size,
                              hipStream_t stream) {
    const float* x  = (const float*)d_in[0];
    const float* Wf = (const float*)d_in[1];
    const float* bf = (const float*)d_in[2];
    const float* Wb = (const float*)d_in[3];
    const float* bb = (const float*)d_in[4];
    float* out = (float*)d_out;
    char* ws = (char*)d_ws;

    const size_t OFF_WPK = 0;                         // 294,912
    const size_t OFF_XT  = 327680;                    // 80,216,064
    const size_t OFF_H0  = OFF_XT + 80216064;         // 10,027,008
    const size_t OFF_H1  = OFF_H0 + 10027008;         // 10,027,008
    const size_t OFF_C   = OFF_H1 + 10027008;         // 8,388,608 (fp16)

    _Float16* wpk = (_Float16*)(ws + OFF_WPK);
    _Float16* xt  = (_Float16*)(ws + OFF_XT);
    _Float16* hb[2] = { (_Float16*)(ws + OFF_H0), (_Float16*)(ws + OFF_H1) };
    _Float16* cst = (_Float16*)(ws + OFF_C);

    hipFuncSetAttribute((const void*)convlstm_step,
                        hipFuncAttributeMaxDynamicSharedMemorySize, 147456);

    // Zero h ping-pong buffers once (out-of-image halo slots must read as 0).
    hipMemsetAsync(ws + OFF_H0, 0, 2u * 10027008u, stream);

    prep_pack<<<dim3(72), dim3(256), 0, stream>>>(Wf, Wb, wpk);
    prep_xtiles<<<dim3(19584), dim3(256), 0, stream>>>(x, xt);

    for (int t = 0; t < S_; ++t) {
        convlstm_step<<<dim3(8, 32), dim3(512), 147456, stream>>>(
            xt, hb[(t + 1) & 1], hb[t & 1], wpk, bf, bb, cst, out, t);
    }
}